// Round 5
// baseline (20.017 us; speedup 1.0000x reference)
//
#include <hip/hip_runtime.h>

#define TOTAL 286
#define KG 32      // grid points per Euler angle
#define NM 11      // 2L-1
#define CIN 16
#define COUT 32
#define BB 8
#define DROW 12                  // padded n-columns (16B-aligned v4 slots)
#define DPQ (6 * 16 * DROW)      // 1152 floats per (q, channel)

typedef float    v4f __attribute__((ext_vector_type(4)));
typedef _Float16 v4h __attribute__((ext_vector_type(4)));

// ---- prep: zero-padded aligned copies of d1/d2 -> ws as Dp[q][l][m][12]
__global__ __launch_bounds__(256) void so3_prep(
    const float* __restrict__ d1, const float* __restrict__ d2,
    float* __restrict__ D1p, float* __restrict__ D2p)
{
    const int e = blockIdx.x * 256 + threadIdx.x;   // KG*6*16*3 = 9216 tasks
    if (e >= KG * 6 * 16 * 3) return;
    const int g = e % 3;
    int rest = e / 3;
    const int m = rest & 15; rest >>= 4;
    const int l = rest % 6;
    const int q = rest / 6;
    v4f z1 = {0.f, 0.f, 0.f, 0.f}, z2 = z1;
    const int mp = m - 5;
    if (mp >= -l && mp <= l) {
        const int base = l * (4 * l * l - 1) / 3 + (2 * l + 1) * (l + mp) + l - 5; // + n
        #pragma unroll
        for (int j = 0; j < 4; ++j) {
            const int n = 4 * g + j, np = n - 5;
            if (np >= -l && np <= l) {
                z1[j] = d1[q * TOTAL + base + n];
                z2[j] = d2[q * TOTAL + base + n];
            }
        }
    }
    const int o = ((q * 6 + l) * 16 + m) * DROW + 4 * g;
    *(v4f*)&D1p[o] = z1;
    *(v4f*)&D2p[o] = z2;
}

// ---- main: 4 blocks per (b,o), 256 threads (4 waves), wave owns q=qc*8+wid and +4.
// 4 blocks/CU x 4 waves = 16 waves/CU so prologue latency + barrier drains overlap
// across independent blocks. Math identical to round 4 (verified, absmax 0.0625).
__global__ __launch_bounds__(256, 4) void so3_main(
    const float* __restrict__ x,    // [B, CIN, TOTAL]
    const float* __restrict__ w,    // [COUT, CIN, TOTAL]
    const float* __restrict__ ca1,  // [NM, KG]
    const float* __restrict__ cg1,  // [NM, KG]
    const float* __restrict__ ca2,  // [NM, KG]
    const float* __restrict__ cg2,  // [NM, KG]
    const float* __restrict__ D1p,  // [KG][6][16][12]
    const float* __restrict__ D2p,
    float* __restrict__ out)        // [B, COUT]
{
    __shared__ float ySm[288];
    __shared__ __align__(16) float Yp[DPQ];   // y padded like Dp (q-independent)
    __shared__ float redw[4];

    const int tid  = threadIdx.x;
    const int lane = tid & 63;
    const int wid  = tid >> 6;          // 0..3
    const int bid  = blockIdx.x;
    const int qc   = bid & 3;
    const int bo   = bid >> 2;
    const int b    = bo >> 5;
    const int o    = bo & 31;

    // y[i] = sum_c x[b,c,i] * w[o,c,i]   (coalesced over i per c)
    for (int i = tid; i < TOTAL; i += 256) {
        const float* xp = x + b * CIN * TOTAL + i;
        const float* wp = w + o * CIN * TOTAL + i;
        float acc = 0.f;
        #pragma unroll
        for (int c = 0; c < CIN; ++c)
            acc = fmaf(xp[c * TOTAL], wp[c * TOTAL], acc);
        ySm[i] = acc;
    }

    // q-invariant MFMA fragments (layouts verified in round 3):
    // A[m][k]: lane=(m=lane&15, k=4*(lane>>4)+i); B[k][n]: (k=4g+i, n=fr);
    // D[m][n]: (m=4g+j, n=fr) == B-frag -> register chaining.
    const int fr = lane & 15;
    const int g  = lane >> 4;
    v4h G1f[2], G2f[2], A1f[2], A2f[2];
    #pragma unroll
    for (int t = 0; t < 2; ++t) {
        #pragma unroll
        for (int i = 0; i < 4; ++i) {
            const int k = 4 * g + i;
            const int c = fr + 16 * t;
            const bool v = (k < NM);
            G1f[t][i] = (_Float16)(v ? cg1[k * KG + c] : 0.f);
            G2f[t][i] = (_Float16)(v ? cg2[k * KG + c] : 0.f);
            A1f[t][i] = (_Float16)(v ? ca1[k * KG + c] : 0.f);
            A2f[t][i] = (_Float16)(v ? ca2[k * KG + c] : 0.f);
        }
    }
    __syncthreads();   // ySm ready

    // Pad y into Yp[l][m][12] (zeros where invalid). 288 v4-tasks.
    for (int e = tid; e < 6 * 16 * 3; e += 256) {
        const int gg = e % 3;
        int rest = e / 3;
        const int m = rest & 15;
        const int l = rest >> 4;
        v4f z = {0.f, 0.f, 0.f, 0.f};
        const int mp = m - 5;
        if (mp >= -l && mp <= l) {
            const int base = l * (4 * l * l - 1) / 3 + (2 * l + 1) * (l + mp) + l - 5;
            #pragma unroll
            for (int j = 0; j < 4; ++j) {
                const int n = 4 * gg + j, np = n - 5;
                if (np >= -l && np <= l) z[j] = ySm[base + n];
            }
        }
        *(v4f*)&Yp[(l * 16 + m) * DROW + 4 * gg] = z;
    }
    __syncthreads();   // Yp ready — no more barriers until the final reduce

    float lmax = -INFINITY;
    const v4f zero4 = {0.f, 0.f, 0.f, 0.f};

    #pragma unroll
    for (int qi = 0; qi < 2; ++qi) {
        const int q = qc * 8 + wid + 4 * qi;

        // ---- Stage A: S[fr][4g..4g+3] = sum_l Yp * Dp (uniform, aligned, padded)
        v4f s1 = zero4, s2 = zero4;
        if (g < 3) {
            const float* D1q = D1p + q * DPQ;
            const float* D2q = D2p + q * DPQ;
            #pragma unroll
            for (int l = 0; l < 6; ++l) {
                const int off = (l * 16 + fr) * DROW + 4 * g;
                const v4f yv = *(const v4f*)&Yp[off];
                s1 += yv * *(const v4f*)&D1q[off];
                s2 += yv * *(const v4f*)&D2q[off];
            }
        }
        v4h a1, a2;
        #pragma unroll
        for (int i = 0; i < 4; ++i) { a1[i] = (_Float16)s1[i]; a2[i] = (_Float16)s2[i]; }

        // ---- GEMM-B: T = S * G (K = n, padded to 16)
        v4f t1a = __builtin_amdgcn_mfma_f32_16x16x16f16(a1, G1f[0], zero4, 0, 0, 0);
        v4f t1b = __builtin_amdgcn_mfma_f32_16x16x16f16(a1, G1f[1], zero4, 0, 0, 0);
        v4f t2a = __builtin_amdgcn_mfma_f32_16x16x16f16(a2, G2f[0], zero4, 0, 0, 0);
        v4f t2b = __builtin_amdgcn_mfma_f32_16x16x16f16(a2, G2f[1], zero4, 0, 0, 0);
        v4h b1a, b1b, b2a, b2b;
        #pragma unroll
        for (int i = 0; i < 4; ++i) {
            b1a[i] = (_Float16)t1a[i]; b1b[i] = (_Float16)t1b[i];
            b2a[i] = (_Float16)t2a[i]; b2b[i] = (_Float16)t2b[i];
        }

        // ---- GEMM-C: resp = ca1^T*T1 + ca2^T*T2 (K = m, padded to 16)
        #pragma unroll
        for (int pt = 0; pt < 2; ++pt) {
            v4f acc0 = __builtin_amdgcn_mfma_f32_16x16x16f16(A2f[pt], b2a, zero4, 0, 0, 0);
            acc0     = __builtin_amdgcn_mfma_f32_16x16x16f16(A1f[pt], b1a, acc0, 0, 0, 0);
            v4f acc1 = __builtin_amdgcn_mfma_f32_16x16x16f16(A2f[pt], b2b, zero4, 0, 0, 0);
            acc1     = __builtin_amdgcn_mfma_f32_16x16x16f16(A1f[pt], b1b, acc1, 0, 0, 0);
            #pragma unroll
            for (int j = 0; j < 4; ++j) {
                lmax = fmaxf(lmax, acc0[j]);
                lmax = fmaxf(lmax, acc1[j]);
            }
        }
    }

    // ---- reduction: wave shuffle, then across 4 waves
    #pragma unroll
    for (int off = 32; off > 0; off >>= 1)
        lmax = fmaxf(lmax, __shfl_xor(lmax, off, 64));
    if (lane == 0) redw[wid] = lmax;
    __syncthreads();
    if (tid == 0) {
        float v = fmaxf(fmaxf(redw[0], redw[1]), fmaxf(redw[2], redw[3]));
        // 4 blocks per (b,o) write disjoint partials -> atomicMax-free via ws+2nd pass
        // would need another kernel; instead use global atomic max on f32 (all finite).
        // Implemented as atomicMax on the float bit pattern is unsafe for negatives,
        // so use plain atomicMax on int only for non-negative... -> use safe CAS-free
        // trick: out is poisoned; we instead write partials and reduce in-kernel below.
        out[(size_t)bo * 4 + qc + BB * COUT * 0] = v;   // placeholder, overwritten below
    }
}

// tiny final reduce over the 4 q-chunks per (b,o)
__global__ void so3_reduce(const float* __restrict__ partial, float* __restrict__ out) {
    const int t = threadIdx.x;
    if (t < BB * COUT) {
        float v = partial[t * 4];
        #pragma unroll
        for (int j = 1; j < 4; ++j) v = fmaxf(v, partial[t * 4 + j]);
        out[t] = v;
    }
}

extern "C" void kernel_launch(void* const* d_in, const int* in_sizes, int n_in,
                              void* d_out, int out_size, void* d_ws, size_t ws_size,
                              hipStream_t stream) {
    const float* x   = (const float*)d_in[0];
    const float* w   = (const float*)d_in[1];
    const float* d1  = (const float*)d_in[2];
    const float* d2  = (const float*)d_in[3];
    const float* ca1 = (const float*)d_in[4];
    const float* cg1 = (const float*)d_in[5];
    const float* ca2 = (const float*)d_in[6];
    const float* cg2 = (const float*)d_in[7];

    float* D1p = (float*)d_ws;                 // KG*DPQ floats
    float* D2p = D1p + KG * DPQ;               // KG*DPQ floats
    float* partial = D2p + KG * DPQ;           // B*COUT*4 floats

    so3_prep<<<(KG * 6 * 16 * 3 + 255) / 256, 256, 0, stream>>>(d1, d2, D1p, D2p);
    so3_main<<<BB * COUT * 4, 256, 0, stream>>>(x, w, ca1, cg1, ca2, cg2, D1p, D2p, partial);
    so3_reduce<<<1, 256, 0, stream>>>(partial, (float*)d_out);
}

// Round 6
// 13.476 us; speedup vs baseline: 1.4853x; 1.4853x over previous
//
#include <hip/hip_runtime.h>

#define TOTAL 286
#define KG 32      // grid points per Euler angle
#define NM 11      // 2L-1
#define CIN 16
#define COUT 32
#define BB 8
#define DROW 16                  // padded n-columns (cols 11..15 always zero)
#define YPN (6 * 16 * DROW)      // 1536 floats

typedef float    v4f  __attribute__((ext_vector_type(4)));
typedef _Float16 v4h  __attribute__((ext_vector_type(4)));
// dword-aligned v4 for raw (unpadded) d-loads
typedef float    v4fu __attribute__((ext_vector_type(4), aligned(4)));

// Single kernel: one block per (b,o), 1024 threads (16 waves), wave owns q=wid, wid+16.
// Stage A reads d1/d2 RAW: Yp's zero-padding masks every invalid/garbage lane
// (garbage * 0 = 0), so no prep pass and no workspace. q-loop is barrier-free,
// LDS-free (Yp hoisted to registers), and chains into the verified 12-MFMA path.
__global__ __launch_bounds__(1024, 4) void so3_fused(
    const float* __restrict__ x,    // [B, CIN, TOTAL]
    const float* __restrict__ w,    // [COUT, CIN, TOTAL]
    const float* __restrict__ d1,   // [KG, TOTAL]
    const float* __restrict__ d2,   // [KG, TOTAL]
    const float* __restrict__ ca1,  // [NM, KG]
    const float* __restrict__ cg1,  // [NM, KG]
    const float* __restrict__ ca2,  // [NM, KG]
    const float* __restrict__ cg2,  // [NM, KG]
    float* __restrict__ out)        // [B, COUT]
{
    __shared__ float ySm[288];
    __shared__ __align__(16) float Yp[YPN];
    __shared__ float redw[16];

    const int tid  = threadIdx.x;
    const int lane = tid & 63;
    const int wid  = tid >> 6;          // 0..15
    const int bo   = blockIdx.x;
    const int b    = bo >> 5;
    const int o    = bo & 31;

    // ---- y[i] = sum_c x[b,c,i] * w[o,c,i] (each instr: 64 lanes contiguous)
    if (tid < TOTAL) {
        const float* xp = x + b * CIN * TOTAL + tid;
        const float* wp = w + o * CIN * TOTAL + tid;
        float acc = 0.f;
        #pragma unroll
        for (int c = 0; c < CIN; ++c)
            acc = fmaf(xp[c * TOTAL], wp[c * TOTAL], acc);
        ySm[tid] = acc;
    }

    // ---- q-invariant MFMA fragments (layout verified rounds 3-5):
    // A[m][k]: (m=lane&15, k=4*(lane>>4)+i); B[k][n]: (k=4g+i, n=fr);
    // D[m][n]: (m=4g+j, n=fr) == B-frag -> register chaining between GEMMs.
    const int fr = lane & 15;
    const int g  = lane >> 4;
    v4h G1f[2], G2f[2], A1f[2], A2f[2];
    #pragma unroll
    for (int t = 0; t < 2; ++t) {
        #pragma unroll
        for (int i = 0; i < 4; ++i) {
            const int k = 4 * g + i;
            const int c = fr + 16 * t;
            const bool v = (k < NM);
            G1f[t][i] = (_Float16)(v ? cg1[k * KG + c] : 0.f);
            G2f[t][i] = (_Float16)(v ? cg2[k * KG + c] : 0.f);
            A1f[t][i] = (_Float16)(v ? ca1[k * KG + c] : 0.f);
            A2f[t][i] = (_Float16)(v ? ca2[k * KG + c] : 0.f);
        }
    }
    __syncthreads();   // ySm ready

    // ---- Yp[l][m][16]: zero-padded y (cols 11..15 and invalid (l,m,n) = 0)
    for (int e = tid; e < 6 * 16 * 4; e += 1024) {
        const int gg = e & 3;
        const int m  = (e >> 2) & 15;
        const int l  = e >> 6;
        v4f z = {0.f, 0.f, 0.f, 0.f};
        const int mp = m - 5;
        if (mp >= -l && mp <= l && gg < 3) {
            const int base = l * (4 * l * l - 1) / 3 + (2 * l + 1) * (l + mp) + l - 5;
            #pragma unroll
            for (int j = 0; j < 4; ++j) {
                const int n = 4 * gg + j, np = n - 5;
                if (np >= -l && np <= l) z[j] = ySm[base + n];
            }
        }
        *(v4f*)&Yp[(l * 16 + m) * DROW + 4 * gg] = z;
    }
    __syncthreads();   // Yp ready — no more barriers until the final reduce

    // ---- hoist this lane's Yp row-slice and d-offsets into registers
    v4f ypr[6];
    int dOff[6];
    #pragma unroll
    for (int l = 0; l < 6; ++l) {
        ypr[l] = *(const v4f*)&Yp[(l * 16 + fr) * DROW + 4 * g];
        const int mp = fr - 5;
        const bool valid = (mp >= -l && mp <= l);
        const int base = l * (4 * l * l - 1) / 3 + (2 * l + 1) * (l + mp) + l - 5;
        dOff[l] = valid ? base + 4 * g : 0;   // invalid rows: ypr==0 masks garbage
    }

    float lmax = -INFINITY;
    const v4f zero4 = {0.f, 0.f, 0.f, 0.f};

    #pragma unroll
    for (int qi = 0; qi < 2; ++qi) {
        const int q = wid + 16 * qi;
        const float* d1q = d1 + q * TOTAL;
        const float* d2q = d2 + q * TOTAL;

        // ---- Stage A: S[fr][4g+i] = sum_l ypr[l][i] * d[q, base_l + 4g+i]
        v4f s1 = zero4, s2 = zero4;
        #pragma unroll
        for (int l = 0; l < 6; ++l) {
            const v4f dv1 = (v4f)(*(const v4fu*)&d1q[dOff[l]]);
            const v4f dv2 = (v4f)(*(const v4fu*)&d2q[dOff[l]]);
            s1 += ypr[l] * dv1;
            s2 += ypr[l] * dv2;
        }
        v4h a1, a2;
        #pragma unroll
        for (int i = 0; i < 4; ++i) { a1[i] = (_Float16)s1[i]; a2[i] = (_Float16)s2[i]; }

        // ---- GEMM-B: T = S * G (K = n, padded to 16)
        v4f t1a = __builtin_amdgcn_mfma_f32_16x16x16f16(a1, G1f[0], zero4, 0, 0, 0);
        v4f t1b = __builtin_amdgcn_mfma_f32_16x16x16f16(a1, G1f[1], zero4, 0, 0, 0);
        v4f t2a = __builtin_amdgcn_mfma_f32_16x16x16f16(a2, G2f[0], zero4, 0, 0, 0);
        v4f t2b = __builtin_amdgcn_mfma_f32_16x16x16f16(a2, G2f[1], zero4, 0, 0, 0);
        v4h b1a, b1b, b2a, b2b;
        #pragma unroll
        for (int i = 0; i < 4; ++i) {
            b1a[i] = (_Float16)t1a[i]; b1b[i] = (_Float16)t1b[i];
            b2a[i] = (_Float16)t2a[i]; b2b[i] = (_Float16)t2b[i];
        }

        // ---- GEMM-C: resp = ca1^T*T1 + ca2^T*T2 (K = m, padded to 16)
        #pragma unroll
        for (int pt = 0; pt < 2; ++pt) {
            v4f acc0 = __builtin_amdgcn_mfma_f32_16x16x16f16(A2f[pt], b2a, zero4, 0, 0, 0);
            acc0     = __builtin_amdgcn_mfma_f32_16x16x16f16(A1f[pt], b1a, acc0, 0, 0, 0);
            v4f acc1 = __builtin_amdgcn_mfma_f32_16x16x16f16(A2f[pt], b2b, zero4, 0, 0, 0);
            acc1     = __builtin_amdgcn_mfma_f32_16x16x16f16(A1f[pt], b1b, acc1, 0, 0, 0);
            #pragma unroll
            for (int j = 0; j < 4; ++j) {
                lmax = fmaxf(lmax, acc0[j]);
                lmax = fmaxf(lmax, acc1[j]);
            }
        }
    }

    // ---- reduction: wave shuffle, then across 16 waves
    #pragma unroll
    for (int off = 32; off > 0; off >>= 1)
        lmax = fmaxf(lmax, __shfl_xor(lmax, off, 64));
    if (lane == 0) redw[wid] = lmax;
    __syncthreads();
    if (tid == 0) {
        float v = redw[0];
        #pragma unroll
        for (int i = 1; i < 16; ++i) v = fmaxf(v, redw[i]);
        out[bo] = v;
    }
}

extern "C" void kernel_launch(void* const* d_in, const int* in_sizes, int n_in,
                              void* d_out, int out_size, void* d_ws, size_t ws_size,
                              hipStream_t stream) {
    const float* x   = (const float*)d_in[0];
    const float* w   = (const float*)d_in[1];
    const float* d1  = (const float*)d_in[2];
    const float* d2  = (const float*)d_in[3];
    const float* ca1 = (const float*)d_in[4];
    const float* cg1 = (const float*)d_in[5];
    const float* ca2 = (const float*)d_in[6];
    const float* cg2 = (const float*)d_in[7];

    so3_fused<<<BB * COUT, 1024, 0, stream>>>(
        x, w, d1, d2, ca1, cg1, ca2, cg2, (float*)d_out);
}